// Round 12
// baseline (326.976 us; speedup 1.0000x reference)
//
#include <hip/hip_runtime.h>
#include <math.h>

// Problem constants (DUQ head)
#define B_      1024
#define EMBED_  768
#define HIDDEN_ 2048
#define C_      200
#define E_      256
#define EPS_    1e-5f
#define NEG_INV_2LS2 (-50.0f)

typedef unsigned short ushort_t;
typedef __attribute__((ext_vector_type(8))) short short8;
typedef __attribute__((ext_vector_type(4))) float f32x4;

__device__ __forceinline__ float gelu_exact(float x) {
    return 0.5f * x * (1.0f + erff(x * 0.70710678118654752f));
}

// round-to-nearest-even float -> bf16 bits
__device__ __forceinline__ ushort_t f2bf(float x) {
    union { float f; unsigned int u; } v; v.f = x;
    unsigned int r = v.u + 0x7fffu + ((v.u >> 16) & 1u);
    return (ushort_t)(r >> 16);
}
__device__ __forceinline__ float bf2f(ushort_t s) {
    union { float f; unsigned int u; } v; v.u = ((unsigned int)s) << 16;
    return v.f;
}

// async global->LDS, 16B per lane; lds base must be wave-uniform.
__device__ __forceinline__ void glds16(const void* g, void* l) {
    __builtin_amdgcn_global_load_lds(
        (const __attribute__((address_space(1))) unsigned int*)g,
        (__attribute__((address_space(3))) unsigned int*)l, 16, 0, 0);
}

// ---------------- LayerNorm -> split bf16 (hi/lo) ----------------
template<int COLS>
__global__ __launch_bounds__(256)
void ln_split_kernel(const float* __restrict__ x, const float* __restrict__ g,
                     const float* __restrict__ b, ushort_t* __restrict__ oh,
                     ushort_t* __restrict__ ol) {
    const int row = blockIdx.x;
    const int tid = threadIdx.x;
    constexpr int NT  = 256;
    constexpr int PER = COLS / NT;
    float v[PER];
    float s = 0.f, s2 = 0.f;
    const float* xr = x + (size_t)row * COLS;
    #pragma unroll
    for (int i = 0; i < PER; ++i) {
        v[i] = xr[tid + i * NT];
        s  += v[i];
        s2 += v[i] * v[i];
    }
    #pragma unroll
    for (int off = 32; off > 0; off >>= 1) {
        s  += __shfl_down(s,  off, 64);
        s2 += __shfl_down(s2, off, 64);
    }
    __shared__ float sbuf[4], s2buf[4], stat[2];
    const int wid = tid >> 6;
    if ((tid & 63) == 0) { sbuf[wid] = s; s2buf[wid] = s2; }
    __syncthreads();
    if (tid == 0) {
        float ts = 0.f, ts2 = 0.f;
        #pragma unroll
        for (int i = 0; i < NT / 64; ++i) { ts += sbuf[i]; ts2 += s2buf[i]; }
        float mu  = ts / COLS;
        float var = ts2 / COLS - mu * mu;
        stat[0] = mu;
        stat[1] = rsqrtf(var + EPS_);
    }
    __syncthreads();
    const float mu = stat[0], rstd = stat[1];
    #pragma unroll
    for (int i = 0; i < PER; ++i) {
        int c = tid + i * NT;
        float y = (v[i] - mu) * rstd * g[c] + b[c];
        ushort_t h = f2bf(y);
        size_t o = (size_t)row * COLS + c;
        oh[o] = h;
        ol[o] = f2bf(y - bf2f(h));
    }
}

// ---------------- transpose + hi/lo split: src [R][Nc] fp32 -> out [Nc][R] bf16 ----
__global__ __launch_bounds__(256)
void tconv_kernel(const float* __restrict__ src, ushort_t* __restrict__ th,
                  ushort_t* __restrict__ tl, int R, int Nc) {
    __shared__ float tile[64][65];
    const size_t base = (size_t)blockIdx.x * R * Nc;
    const int ntx = Nc >> 6;
    const int ky = blockIdx.y / ntx, nx = blockIdx.y % ntx;
    const int tid = threadIdx.x;
    const int col = tid & 63, rr = tid >> 6;
    const float* s = src + base + (size_t)(ky * 64) * Nc + nx * 64;
    #pragma unroll
    for (int i = 0; i < 16; ++i) {
        int r = i * 4 + rr;
        tile[r][col] = s[(size_t)r * Nc + col];
    }
    __syncthreads();
    #pragma unroll
    for (int i = 0; i < 16; ++i) {
        int dl = i * 4 + rr;
        float x = tile[col][dl];            // stride-65 read: conflict-free
        ushort_t h = f2bf(x);
        size_t o = base + (size_t)(nx * 64 + dl) * R + ky * 64 + col;
        th[o] = h;
        tl[o] = f2bf(x - bf2f(h));
    }
}

// ---------------- bf16x3 MFMA GEMM: out = act(A @ W + bias) ----------------
// (unchanged — rows are 128B with XOR-8, conflict-free)
template<int MREP, int ACT, int OUT_SPLIT>
__global__ __launch_bounds__(256)
void mfma_gemm_kernel(const ushort_t* __restrict__ Ah, const ushort_t* __restrict__ Al,
                      const ushort_t* __restrict__ Wh, const ushort_t* __restrict__ Wl,
                      const float* __restrict__ bias,
                      float* __restrict__ outF, ushort_t* __restrict__ Oh,
                      ushort_t* __restrict__ Ol, int M, int N, int K) {
    constexpr int BM = MREP * 32;
    __shared__ short AsH[BM * 64], AsL[BM * 64];
    __shared__ short BsH[64 * 64], BsL[64 * 64];
    const int tid  = threadIdx.x;
    const int lane = tid & 63;
    const int w    = tid >> 6;
    const int wr = w >> 1, wc = w & 1;
    const int fr = lane & 15, fg = lane >> 4;

    const int nblk = gridDim.x, chunk = nblk >> 3;
    const int wg = (blockIdx.x & 7) * chunk + (blockIdx.x >> 3);
    const int gy = M / BM;
    const int cx = wg / gy, ry = wg % gy;
    const int row0 = ry * BM, col0 = cx * 64;

    const int srow  = tid >> 3;
    const int sslot = (tid & 7) ^ (srow & 7);
    const size_t aoff = (size_t)(row0 + srow) * K + sslot * 8;
    const size_t boff = (size_t)(col0 + srow) * K + sslot * 8;

    f32x4 acc[MREP][2];
    #pragma unroll
    for (int m = 0; m < MREP; ++m)
        #pragma unroll
        for (int n = 0; n < 2; ++n) acc[m][n] = (f32x4){0.f, 0.f, 0.f, 0.f};

    for (int k0 = 0; k0 < K; k0 += 64) {
        #pragma unroll
        for (int p = 0; p < BM / 32; ++p) {
            glds16(Ah + aoff + (size_t)p * 32 * K + k0, &AsH[p * 2048 + w * 512]);
            glds16(Al + aoff + (size_t)p * 32 * K + k0, &AsL[p * 2048 + w * 512]);
        }
        #pragma unroll
        for (int p = 0; p < 2; ++p) {
            glds16(Wh + boff + (size_t)p * 32 * K + k0, &BsH[p * 2048 + w * 512]);
            glds16(Wl + boff + (size_t)p * 32 * K + k0, &BsL[p * 2048 + w * 512]);
        }
        __syncthreads();
        #pragma unroll
        for (int ks = 0; ks < 2; ++ks) {
            short8 bh[2], bl[2];
            #pragma unroll
            for (int n = 0; n < 2; ++n) {
                int rB = wc * 32 + n * 16 + fr;
                int sl = ((ks * 4 + fg) ^ (rB & 7)) << 3;
                bh[n] = *(const short8*)&BsH[rB * 64 + sl];
                bl[n] = *(const short8*)&BsL[rB * 64 + sl];
            }
            #pragma unroll
            for (int m = 0; m < MREP; ++m) {
                int rA = wr * MREP * 16 + m * 16 + fr;
                int sl = ((ks * 4 + fg) ^ (rA & 7)) << 3;
                short8 ah = *(const short8*)&AsH[rA * 64 + sl];
                short8 al = *(const short8*)&AsL[rA * 64 + sl];
                #pragma unroll
                for (int n = 0; n < 2; ++n) {
                    acc[m][n] = __builtin_amdgcn_mfma_f32_16x16x32_bf16(ah, bh[n], acc[m][n], 0, 0, 0);
                    acc[m][n] = __builtin_amdgcn_mfma_f32_16x16x32_bf16(ah, bl[n], acc[m][n], 0, 0, 0);
                    acc[m][n] = __builtin_amdgcn_mfma_f32_16x16x32_bf16(al, bh[n], acc[m][n], 0, 0, 0);
                }
            }
        }
        __syncthreads();
    }

    #pragma unroll
    for (int n = 0; n < 2; ++n) {
        int col = col0 + wc * 32 + n * 16 + fr;
        float bv = bias[col];
        #pragma unroll
        for (int m = 0; m < MREP; ++m) {
            #pragma unroll
            for (int r = 0; r < 4; ++r) {
                int row = row0 + wr * MREP * 16 + m * 16 + fg * 4 + r;
                float v = acc[m][n][r] + bv;
                if (ACT) v = gelu_exact(v);
                size_t o = (size_t)row * N + col;
                if (OUT_SPLIT) {
                    ushort_t h = f2bf(v);
                    Oh[o] = h;
                    Ol[o] = f2bf(v - bf2f(h));
                } else {
                    outF[o] = v;
                }
            }
        }
    }
}

// ---------------- per-class RBF distance via bf16x3 MFMA ----------------
// v3: BM=128 rows/block, 512 thr (8 waves, 2 row x 4 d quadrants).
//     Interleaved hi|lo 128B rows (XOR-8) + counted-vmcnt double buffer.
// LDS 96KB (shorts): A[2][8192] @0, B[2][16384] @16384; red aliases A buf0.
__global__ __launch_bounds__(512)
void rbf_mfma_kernel(const ushort_t* __restrict__ zh,
                     const ushort_t* __restrict__ zl,
                     const ushort_t* __restrict__ cwh,
                     const ushort_t* __restrict__ cwl,
                     const float* __restrict__ cent,
                     float* __restrict__ logk) {
    extern __shared__ short smem[];   // 49152 shorts = 96KB
    const int tid  = threadIdx.x;
    const int lane = tid & 63;
    const int w    = tid >> 6;        // 0..7
    const int wr   = w >> 2;          // row half: 0..1
    const int wc   = w & 3;           // d quadrant: 0..3
    const int fr   = lane & 15;
    const int fg   = lane >> 4;

    // XCD-chunked swizzle: 1600 blocks, 200/chunk; 8 blocks per class.
    const int bid = blockIdx.x;
    const int wg  = (bid & 7) * 200 + (bid >> 3);
    const int c    = wg >> 3;
    const int row0 = (wg & 7) * 128;

    // staging: row = tid>>3 (0..63), slot = tid&7; logical chunk ss = slot^(row&7)
    // ss<4 -> hi k-group ss; ss>=4 -> lo k-group ss-4.
    const int srow = tid >> 3;
    const int ss   = (tid & 7) ^ (srow & 7);
    const int kofs = (ss & 3) * 8;
    const ushort_t* zsel  = (ss < 4) ? zh  : zl;
    const ushort_t* cwsel = (ss < 4) ? cwh : cwl;
    const ushort_t* gA = zsel  + (size_t)(row0 + srow) * E_ + kofs;
    const ushort_t* gB = cwsel + (size_t)c * 65536 + (size_t)srow * E_ + kofs;

    f32x4 acc[4][4];
    #pragma unroll
    for (int m = 0; m < 4; ++m)
        #pragma unroll
        for (int n = 0; n < 4; ++n)
            acc[m][n] = (f32x4){0.f, 0.f, 0.f, 0.f};

    // --- staging: 6 glds per wave per tile (A: 2, B: 4) ---
    auto STAGE = [&](int t, int buf) {
        const int ke = t * 32;
        #pragma unroll
        for (int i = 0; i < 2; ++i)
            glds16(gA + (size_t)i * 64 * E_ + ke,
                   &smem[buf * 8192 + i * 4096 + w * 512]);
        #pragma unroll
        for (int i = 0; i < 4; ++i)
            glds16(gB + (size_t)i * 64 * E_ + ke,
                   &smem[16384 + buf * 16384 + i * 4096 + w * 512]);
    };

    auto COMPUTE = [&](int buf) {
        const short* Ab = &smem[buf * 8192];
        const short* Bb = &smem[16384 + buf * 16384];
        short8 bh[4], bl[4];
        #pragma unroll
        for (int n = 0; n < 4; ++n) {
            int d = wc * 64 + n * 16 + fr;
            bh[n] = *(const short8*)&Bb[d * 64 + ((fg       ^ (d & 7)) << 3)];
            bl[n] = *(const short8*)&Bb[d * 64 + (((4 + fg) ^ (d & 7)) << 3)];
        }
        #pragma unroll
        for (int m = 0; m < 4; ++m) {
            int r = wr * 64 + m * 16 + fr;
            short8 ah = *(const short8*)&Ab[r * 64 + ((fg       ^ (r & 7)) << 3)];
            short8 al = *(const short8*)&Ab[r * 64 + (((4 + fg) ^ (r & 7)) << 3)];
            #pragma unroll
            for (int n = 0; n < 4; ++n) {
                acc[m][n] = __builtin_amdgcn_mfma_f32_16x16x32_bf16(ah, bh[n], acc[m][n], 0, 0, 0);
                acc[m][n] = __builtin_amdgcn_mfma_f32_16x16x32_bf16(ah, bl[n], acc[m][n], 0, 0, 0);
                acc[m][n] = __builtin_amdgcn_mfma_f32_16x16x32_bf16(al, bh[n], acc[m][n], 0, 0, 0);
            }
        }
    };

    // --- pipelined K loop: 8 tiles of BK=32 (6 glds/wave each) ---
    STAGE(0, 0);                                    // 6 outstanding
    for (int t = 0; t < 7; ++t) {
        STAGE(t + 1, (t + 1) & 1);                  // 12 outstanding
        asm volatile("s_waitcnt vmcnt(6)" ::: "memory");   // tile t landed
        __builtin_amdgcn_s_barrier();
        __builtin_amdgcn_sched_barrier(0);
        COMPUTE(t & 1);
        __builtin_amdgcn_s_barrier();               // reads done before overwrite
    }
    asm volatile("s_waitcnt vmcnt(0)" ::: "memory");
    __builtin_amdgcn_s_barrier();
    __builtin_amdgcn_sched_barrier(0);
    COMPUTE(1);

    // --- epilogue: dist_sq per row ---
    float cmu[4];
    #pragma unroll
    for (int n = 0; n < 4; ++n) cmu[n] = cent[(size_t)c * E_ + wc * 64 + n * 16 + fr];

    // red[128][4] floats aliases A buf0 (2KB); buf0 reads finished at t=6 barrier,
    // final COMPUTE reads buf1 only (disjoint).
    float* red = (float*)smem;
    #pragma unroll
    for (int m = 0; m < 4; ++m) {
        #pragma unroll
        for (int r = 0; r < 4; ++r) {
            float p = 0.f;
            #pragma unroll
            for (int n = 0; n < 4; ++n) {
                float d = acc[m][n][r] - cmu[n];
                p = fmaf(d, d, p);
            }
            p += __shfl_xor(p, 1, 64);
            p += __shfl_xor(p, 2, 64);
            p += __shfl_xor(p, 4, 64);
            p += __shfl_xor(p, 8, 64);
            if (fr == 0) red[(wr * 64 + m * 16 + fg * 4 + r) * 4 + wc] = p;
        }
    }
    __syncthreads();
    if (tid < 128) {
        float s = red[tid * 4 + 0] + red[tid * 4 + 1] + red[tid * 4 + 2] + red[tid * 4 + 3];
        logk[(size_t)(row0 + tid) * C_ + c] = NEG_INV_2LS2 * s;
    }
}

// ---------------- softmax + outputs ----------------
__global__ __launch_bounds__(64)
void out_kernel(const float* __restrict__ logk, float* __restrict__ dout) {
    const int b = blockIdx.x;
    const int t = threadIdx.x;
    const float* lr = logk + (size_t)b * C_;
    float v[4];
    float m = -INFINITY;
    #pragma unroll
    for (int i = 0; i < 4; ++i) {
        int idx = t + i * 64;
        v[i] = (idx < C_) ? lr[idx] : -INFINITY;
        m = fmaxf(m, v[i]);
    }
    #pragma unroll
    for (int off = 32; off > 0; off >>= 1) m = fmaxf(m, __shfl_xor(m, off, 64));
    float s = 0.f;
    #pragma unroll
    for (int i = 0; i < 4; ++i) {
        int idx = t + i * 64;
        if (idx < C_) s += expf(v[i] - m);
    }
    #pragma unroll
    for (int off = 32; off > 0; off >>= 1) s += __shfl_xor(s, off, 64);
    const float inv = 1.0f / s;
    #pragma unroll
    for (int i = 0; i < 4; ++i) {
        int idx = t + i * 64;
        if (idx < C_) {
            float p = expf(v[i] - m) * inv;
            dout[(size_t)b * C_ + idx] = p;
            dout[(size_t)204800 + (size_t)b * C_ + idx] = p;
            dout[(size_t)409600 + (size_t)b * C_ + idx] = expf(v[i]);
        }
    }
    if (t == 0) dout[(size_t)614400 + b] = 1.0f - expf(m);
}

// ---------------- launcher ----------------
extern "C" void kernel_launch(void* const* d_in, const int* in_sizes, int n_in,
                              void* d_out, int out_size, void* d_ws, size_t ws_size,
                              hipStream_t stream) {
    const float* features = (const float*)d_in[0];
    const float* ln1_g = (const float*)d_in[1];
    const float* ln1_b = (const float*)d_in[2];
    const float* W1    = (const float*)d_in[3];
    const float* b1    = (const float*)d_in[4];
    const float* ln2_g = (const float*)d_in[5];
    const float* ln2_b = (const float*)d_in[6];
    const float* W2    = (const float*)d_in[7];
    const float* b2    = (const float*)d_in[8];
    const float* W3    = (const float*)d_in[9];
    const float* b3    = (const float*)d_in[10];
    const float* cw    = (const float*)d_in[11];
    const float* cent  = (const float*)d_in[12];
    float* out = (float*)d_out;
    float* ws  = (float*)d_ws;

    // fp32 scratch
    float* h1 = ws;                       // [B, HIDDEN]
    float* lk = ws + 2097152;             // [B, C]
    // bf16 split scratch
    ushort_t* u = (ushort_t*)(ws + 2097152 + 204800);
    size_t o = 0;
    ushort_t* h0h = u + o; o += (size_t)B_ * EMBED_;
    ushort_t* h0l = u + o; o += (size_t)B_ * EMBED_;
    ushort_t* h1h = u + o; o += (size_t)B_ * HIDDEN_;
    ushort_t* h1l = u + o; o += (size_t)B_ * HIDDEN_;
    ushort_t* h2h = u + o; o += (size_t)B_ * HIDDEN_;
    ushort_t* h2l = u + o; o += (size_t)B_ * HIDDEN_;
    ushort_t* zh  = u + o; o += (size_t)B_ * E_;
    ushort_t* zl  = u + o; o += (size_t)B_ * E_;
    ushort_t* w1h = u + o; o += (size_t)EMBED_ * HIDDEN_;
    ushort_t* w1l = u + o; o += (size_t)EMBED_ * HIDDEN_;
    ushort_t* w2h = u + o; o += (size_t)HIDDEN_ * HIDDEN_;
    ushort_t* w2l = u + o; o += (size_t)HIDDEN_ * HIDDEN_;
    ushort_t* w3h = u + o; o += (size_t)HIDDEN_ * E_;
    ushort_t* w3l = u + o; o += (size_t)HIDDEN_ * E_;
    ushort_t* cwh = u + o; o += (size_t)C_ * E_ * E_;
    ushort_t* cwl = u + o; o += (size_t)C_ * E_ * E_;

    // weight conversions (input-only dependencies) first
    tconv_kernel<<<dim3(C_, 16), 256, 0, stream>>>(cw, cwh, cwl, E_, E_);
    tconv_kernel<<<dim3(1, (EMBED_ / 64) * (HIDDEN_ / 64)), 256, 0, stream>>>(W1, w1h, w1l, EMBED_, HIDDEN_);
    tconv_kernel<<<dim3(1, (HIDDEN_ / 64) * (HIDDEN_ / 64)), 256, 0, stream>>>(W2, w2h, w2l, HIDDEN_, HIDDEN_);
    tconv_kernel<<<dim3(1, (HIDDEN_ / 64) * (E_ / 64)), 256, 0, stream>>>(W3, w3h, w3l, HIDDEN_, E_);

    ln_split_kernel<EMBED_><<<B_, 256, 0, stream>>>(features, ln1_g, ln1_b, h0h, h0l);

    mfma_gemm_kernel<2, 1, 0><<<(HIDDEN_ / 64) * (B_ / 64), 256, 0, stream>>>(
        h0h, h0l, w1h, w1l, b1, h1, nullptr, nullptr, B_, HIDDEN_, EMBED_);

    ln_split_kernel<HIDDEN_><<<B_, 256, 0, stream>>>(h1, ln2_g, ln2_b, h1h, h1l);

    mfma_gemm_kernel<2, 1, 1><<<(HIDDEN_ / 64) * (B_ / 64), 256, 0, stream>>>(
        h1h, h1l, w2h, w2l, b2, nullptr, h2h, h2l, B_, HIDDEN_, HIDDEN_);

    mfma_gemm_kernel<1, 0, 1><<<(E_ / 64) * (B_ / 32), 256, 0, stream>>>(
        h2h, h2l, w3h, w3l, b3, nullptr, zh, zl, B_, E_, HIDDEN_);

    rbf_mfma_kernel<<<1600, 512, 98304, stream>>>(zh, zl, cwh, cwl, cent, lk);

    out_kernel<<<B_, 64, 0, stream>>>(lk, out);
}